// Round 5
// baseline (262.860 us; speedup 1.0000x reference)
//
#include <hip/hip_runtime.h>
#include <stdint.h>

// ---- types ----
typedef unsigned short u16;
typedef __attribute__((ext_vector_type(4))) float f32x4;
typedef __attribute__((ext_vector_type(8))) __bf16 bf16x8;
typedef __attribute__((ext_vector_type(4))) unsigned int u32x4;

#define HWPX 4096   // H*W pixels
#define NMEM 8192   // T*H*W memory slots
#define CKD  64
#define VROWS 1024  // NOBJ*CV

__device__ __forceinline__ u16 f2bf(float x) {
    union { float f; unsigned u; } v; v.f = x;
    unsigned r = v.u + 0x7FFFu + ((v.u >> 16) & 1u);
    return (u16)(r >> 16);
}

// async global->LDS, 16B per lane; lds base wave-uniform (HW adds lane*16)
__device__ __forceinline__ void gld_lds16(const void* g, void* l) {
    __builtin_amdgcn_global_load_lds(
        (const __attribute__((address_space(1))) uint32_t*)g,
        (__attribute__((address_space(3))) uint32_t*)l, 16, 0, 0);
}

// ---------------- fused prep: q (16 blocks) | k (32 blocks) | mv (8192 blocks) ----
__global__ void prep_all(const float* __restrict__ qk, const float* __restrict__ qe,
                         const float* __restrict__ mk, const float* __restrict__ mv,
                         u16* __restrict__ Qhat, float* __restrict__ bsq,
                         u16* __restrict__ Khat, u16* __restrict__ mvb,
                         float* __restrict__ denom) {
    const int bx = blockIdx.x;
    const int tid = threadIdx.x;
    if (bx < 16) {
        int p = bx * 256 + tid;   // 4096
        float acc = 0.f;
        #pragma unroll 4
        for (int c = 0; c < CKD; ++c) {
            float k = qk[c * HWPX + p];
            float e = qe[c * HWPX + p];
            Qhat[p * 128 + c]      = f2bf(k * e);
            Qhat[p * 128 + 64 + c] = f2bf(e);
            acc += e * k * k;
        }
        bsq[p] = acc;
        denom[p] = 0.f;
    } else if (bx < 48) {
        int n = (bx - 16) * 256 + tid;   // 8192
        #pragma unroll 4
        for (int c = 0; c < CKD; ++c) {
            float m = mk[c * NMEM + n];
            Khat[n * 128 + c]      = f2bf(2.f * m);
            Khat[n * 128 + 64 + c] = f2bf(-m * m);
        }
    } else {
        int i = (bx - 48) * 256 + tid;   // 2M iterations, 4 floats each
        float4 v = ((const float4*)mv)[i];
        u16 o0 = f2bf(v.x), o1 = f2bf(v.y), o2 = f2bf(v.z), o3 = f2bf(v.w);
        unsigned lo = (unsigned)o0 | ((unsigned)o1 << 16);
        unsigned hi = (unsigned)o2 | ((unsigned)o3 << 16);
        ((uint2*)mvb)[i] = make_uint2(lo, hi);
    }
}

// ---------------- GEMM1: S = Qhat(4096x128) * Khat(8192x128)^T ----------------
// NO input LDS staging: Qhat(1MB)/Khat(2MB) are L2/L3-resident and each MFMA
// fragment is a contiguous 16B chunk -> direct global_load_dwordx4 into VGPRs,
// zero barriers before the epilogue. LDS holds only the Ps transpose buffer
// (128x136 u16 = 34KB) -> 4 blocks/CU. Epilogue: P = exp((S-bsq)*ms*0.125),
// denom via 16-lane butterfly + ONE atomicAdd/thread, tiled Pt store
// [pb][nb][128][128] (32KB contiguous per block).
__launch_bounds__(256, 4)
__global__ void gemm1_kernel(const u16* __restrict__ Qhat, const u16* __restrict__ Khat,
                             const float* __restrict__ bsq, const float* __restrict__ ms,
                             u16* __restrict__ Pt, float* __restrict__ denom) {
    __shared__ __align__(16) u16 Ps[128 * 136];

    const int tid  = threadIdx.x;
    const int l    = tid & 63;
    const int w    = tid >> 6;
    const int quad = l >> 4;
    const int l15  = l & 15;
    const int wm = w >> 1, wn = w & 1;
    const int p0 = blockIdx.x * 128;
    const int n0 = blockIdx.y * 128;

    // fragment base pointers: row = (tile + wave_sub + mi*16 + l15), k = kk*32 + quad*8
    const u16* aBase = Qhat + (size_t)(p0 + wm * 64 + l15) * 128 + quad * 8;
    const u16* bBase = Khat + (size_t)(n0 + wn * 64 + l15) * 128 + quad * 8;

    f32x4 acc[4][4] = {};
    #pragma unroll
    for (int kk = 0; kk < 4; ++kk) {
        bf16x8 a[4], b[4];
        #pragma unroll
        for (int mi = 0; mi < 4; ++mi)
            a[mi] = *(const bf16x8*)(aBase + mi * 16 * 128 + kk * 32);
        #pragma unroll
        for (int ni = 0; ni < 4; ++ni)
            b[ni] = *(const bf16x8*)(bBase + ni * 16 * 128 + kk * 32);
        #pragma unroll
        for (int mi = 0; mi < 4; ++mi)
            #pragma unroll
            for (int ni = 0; ni < 4; ++ni)
                acc[mi][ni] = __builtin_amdgcn_mfma_f32_16x16x32_bf16(a[mi], b[ni], acc[mi][ni], 0, 0, 0);
    }

    // per-lane epilogue constants
    float msv[4];
    #pragma unroll
    for (int ni = 0; ni < 4; ++ni)
        msv[ni] = ms[n0 + wn * 64 + ni * 16 + l15] * 0.125f;
    float bsv[4][4];
    #pragma unroll
    for (int mi = 0; mi < 4; ++mi)
        #pragma unroll
        for (int r = 0; r < 4; ++r)
            bsv[mi][r] = bsq[p0 + wm * 64 + mi * 16 + quad * 4 + r];

    float rowsum[4][4] = {};     // [mi][r] partial over this lane's 4 cols
    #pragma unroll
    for (int mi = 0; mi < 4; ++mi) {
        #pragma unroll
        for (int ni = 0; ni < 4; ++ni) {
            f32x4 v = acc[mi][ni];
            int col = wn * 64 + ni * 16 + l15;
            #pragma unroll
            for (int r = 0; r < 4; ++r) {
                int rowl = wm * 64 + mi * 16 + quad * 4 + r;
                float pv = __expf((v[r] - bsv[mi][r]) * msv[ni]);
                rowsum[mi][r] += pv;
                Ps[rowl * 136 + col] = f2bf(pv);
            }
        }
    }
    // butterfly full-reduce over the 16-lane l15 group (all lanes get all sums)
    #pragma unroll
    for (int mi = 0; mi < 4; ++mi)
        #pragma unroll
        for (int r = 0; r < 4; ++r) {
            float s = rowsum[mi][r];
            s += __shfl_xor(s, 1);
            s += __shfl_xor(s, 2);
            s += __shfl_xor(s, 4);
            s += __shfl_xor(s, 8);
            rowsum[mi][r] = s;
        }
    // one atomic per thread: lane l15 owns (mi,r) = (l15>>2, l15&3)
    {
        float myv = 0.f;
        #pragma unroll
        for (int mi = 0; mi < 4; ++mi)
            #pragma unroll
            for (int r = 0; r < 4; ++r)
                if (l15 == mi * 4 + r) myv = rowsum[mi][r];
        atomicAdd(&denom[p0 + wm * 64 + (l15 >> 2) * 16 + quad * 4 + (l15 & 3)], myv);
    }
    __syncthreads();

    // tiled Pt store: 32 KB contiguous per block
    {
        const size_t tileOff = ((size_t)blockIdx.x * 64 + blockIdx.y) * 16384;
        int row = tid >> 1, half = tid & 1;
        const u32x4* src = (const u32x4*)(Ps + row * 136 + half * 64);
        u32x4* dst = (u32x4*)(Pt + tileOff + row * 128 + half * 64);
        #pragma unroll
        for (int i = 0; i < 8; ++i) dst[i] = src[i];
    }
}

// ---------------- GEMM2: outacc += mv_bf16(1024x8192) * Pt_tiled^T ----------------
// Split-K=4: 1024 blocks = 4 blocks/CU. XCD swizzle: linear id bits
// [2:0]=p_lo [5:3]=v [7:6]=p_hi [9:8]=kz so the 8 v-blocks sharing a Pt slab
// are 8 ids apart -> same XCD L2 (FETCH 271->103 MB measured). fp32 atomicAdd.
__launch_bounds__(256, 4)
__global__ void gemm2_kernel(const u16* __restrict__ Ab, const u16* __restrict__ Bt,
                             float* __restrict__ outacc) {
    __shared__ __align__(16) u16 As[128 * 64];
    __shared__ __align__(16) u16 Bs[128 * 64];

    const int tid  = threadIdx.x;
    const int l    = tid & 63;
    const int w    = tid >> 6;
    const int quad = l >> 4;
    const int l15  = l & 15;
    const int wm = w >> 1, wn = w & 1;

    const int lin = blockIdx.x + (blockIdx.y << 3) + (blockIdx.z << 8);
    const int vb  = (lin >> 3) & 7;
    const int pb  = (lin & 7) | (((lin >> 6) & 3) << 3);
    const int kz  = lin >> 8;
    const int v0 = vb * 128;
    const int p0 = pb * 128;
    const int kbeg = kz * (NMEM / 4);
    const int kend = kbeg + (NMEM / 4);

    const int rsub = tid >> 3;                      // 0..31
    const int csw  = (tid & 7) ^ (rsub & 7);        // swizzled source chunk

    f32x4 acc[4][4] = {};

    for (int k0 = kbeg; k0 < kend; k0 += 64) {
        const int nb = k0 >> 7;
        const int nh = (k0 >> 6) & 1;
        const u16* bsrc = Bt + ((size_t)pb * 64 + nb) * 16384 + nh * 64;
        __syncthreads();
        #pragma unroll
        for (int rnd = 0; rnd < 4; ++rnd) {
            gld_lds16(Ab + (size_t)(v0 + rnd * 32 + rsub) * NMEM + k0 + csw * 8,
                      As + rnd * 2048 + w * 512);
            gld_lds16(bsrc + (rnd * 32 + rsub) * 128 + csw * 8,
                      Bs + rnd * 2048 + w * 512);
        }
        __syncthreads();
        #pragma unroll
        for (int kk = 0; kk < 2; ++kk) {
            bf16x8 a[4], b[4];
            #pragma unroll
            for (int mi = 0; mi < 4; ++mi) {
                int row = wm * 64 + mi * 16 + l15;
                a[mi] = *(const bf16x8*)(As + row * 64 + (((kk * 4 + quad) ^ (l15 & 7)) << 3));
            }
            #pragma unroll
            for (int ni = 0; ni < 4; ++ni) {
                int row = wn * 64 + ni * 16 + l15;
                b[ni] = *(const bf16x8*)(Bs + row * 64 + (((kk * 4 + quad) ^ (l15 & 7)) << 3));
            }
            #pragma unroll
            for (int mi = 0; mi < 4; ++mi)
                #pragma unroll
                for (int ni = 0; ni < 4; ++ni)
                    acc[mi][ni] = __builtin_amdgcn_mfma_f32_16x16x32_bf16(a[mi], b[ni], acc[mi][ni], 0, 0, 0);
        }
    }

    #pragma unroll
    for (int mi = 0; mi < 4; ++mi) {
        #pragma unroll
        for (int ni = 0; ni < 4; ++ni) {
            int col = p0 + wn * 64 + ni * 16 + l15;
            f32x4 v = acc[mi][ni];
            #pragma unroll
            for (int r = 0; r < 4; ++r) {
                int row = v0 + wm * 64 + mi * 16 + quad * 4 + r;
                atomicAdd(&outacc[(size_t)row * HWPX + col], v[r]);
            }
        }
    }
}

// out[i] /= denom[col], vectorized float4
__global__ void divide_out(float* __restrict__ out, const float* __restrict__ denom) {
    int f = blockIdx.x * 256 + threadIdx.x;     // 1M float4s
    float4 v = ((float4*)out)[f];
    int p4 = f & (HWPX / 4 - 1);
    float4 d = ((const float4*)denom)[p4];
    v.x /= d.x; v.y /= d.y; v.z /= d.z; v.w /= d.w;
    ((float4*)out)[f] = v;
}

// ---------------- launch ----------------
extern "C" void kernel_launch(void* const* d_in, const int* in_sizes, int n_in,
                              void* d_out, int out_size, void* d_ws, size_t ws_size,
                              hipStream_t stream) {
    const float* qk = (const float*)d_in[0];  // (1,64,64,64)
    const float* qe = (const float*)d_in[1];  // (1,64,64,64)
    const float* mk = (const float*)d_in[2];  // (1,64,2,64,64)
    const float* ms = (const float*)d_in[3];  // (1,1,2,64,64)
    const float* mv = (const float*)d_in[4];  // (1,2,512,2,64,64)
    float* out = (float*)d_out;               // (1,2,512,64,64)

    char* ws = (char*)d_ws;
    u16*   Pt    = (u16*)ws;                               // 64 MB  tiled [32][64][128][128] bf16
    u16*   mvb   = (u16*)(ws + ((size_t)64 << 20));        // 16 MB  [1024][8192] bf16
    u16*   Khat  = (u16*)(ws + ((size_t)80 << 20));        // 2 MB   [8192][128]  bf16
    u16*   Qhat  = (u16*)(ws + ((size_t)82 << 20));        // 1 MB   [4096][128]  bf16
    float* bsq   = (float*)(ws + ((size_t)83 << 20));      // 16 KB
    float* denom = (float*)(ws + ((size_t)83 << 20) + 65536); // 16 KB

    hipMemsetAsync(out, 0, (size_t)VROWS * HWPX * sizeof(float), stream);
    prep_all<<<48 + 8192, 256, 0, stream>>>(qk, qe, mk, mv, Qhat, bsq, Khat, mvb, denom);

    dim3 g1(HWPX / 128, NMEM / 128);   // (32, 64)
    gemm1_kernel<<<g1, 256, 0, stream>>>(Qhat, Khat, bsq, ms, Pt, denom);

    dim3 g2(8, 32, 4);  // 1024 blocks, swizzled decode inside
    gemm2_kernel<<<g2, 256, 0, stream>>>(mvb, Pt, out);

    divide_out<<<(VROWS * HWPX / 4) / 256, 256, 0, stream>>>(out, denom);
}

// Round 6
// 232.959 us; speedup vs baseline: 1.1284x; 1.1284x over previous
//
#include <hip/hip_runtime.h>
#include <stdint.h>

// ---- types ----
typedef unsigned short u16;
typedef __attribute__((ext_vector_type(4))) float f32x4;
typedef __attribute__((ext_vector_type(8))) __bf16 bf16x8;
typedef __attribute__((ext_vector_type(4))) unsigned int u32x4;

#define HWPX 4096   // H*W pixels
#define NMEM 8192   // T*H*W memory slots
#define CKD  64
#define VROWS 1024  // NOBJ*CV

__device__ __forceinline__ u16 f2bf(float x) {
    union { float f; unsigned u; } v; v.f = x;
    unsigned r = v.u + 0x7FFFu + ((v.u >> 16) & 1u);
    return (u16)(r >> 16);
}

// async global->LDS, 16B per lane; lds base wave-uniform (HW adds lane*16)
__device__ __forceinline__ void gld_lds16(const void* g, void* l) {
    __builtin_amdgcn_global_load_lds(
        (const __attribute__((address_space(1))) uint32_t*)g,
        (__attribute__((address_space(3))) uint32_t*)l, 16, 0, 0);
}

// -------- fused prep: q (16) | k (32) | mv (8192) | zero-out (4096) --------
__global__ void prep_all(const float* __restrict__ qk, const float* __restrict__ qe,
                         const float* __restrict__ mk, const float* __restrict__ mv,
                         u16* __restrict__ Qhat, float* __restrict__ bsq,
                         u16* __restrict__ Khat, u16* __restrict__ mvb,
                         float* __restrict__ denom, float* __restrict__ outz) {
    const int bx = blockIdx.x;
    const int tid = threadIdx.x;
    if (bx < 16) {
        int p = bx * 256 + tid;   // 4096
        float acc = 0.f;
        #pragma unroll 4
        for (int c = 0; c < CKD; ++c) {
            float k = qk[c * HWPX + p];
            float e = qe[c * HWPX + p];
            Qhat[p * 128 + c]      = f2bf(k * e);
            Qhat[p * 128 + 64 + c] = f2bf(e);
            acc += e * k * k;
        }
        bsq[p] = acc;
        denom[p] = 0.f;
    } else if (bx < 48) {
        int n = (bx - 16) * 256 + tid;   // 8192
        #pragma unroll 4
        for (int c = 0; c < CKD; ++c) {
            float m = mk[c * NMEM + n];
            Khat[n * 128 + c]      = f2bf(2.f * m);
            Khat[n * 128 + 64 + c] = f2bf(-m * m);
        }
    } else if (bx < 48 + 8192) {
        int i = (bx - 48) * 256 + tid;   // 2M iterations, 4 floats each
        float4 v = ((const float4*)mv)[i];
        u16 o0 = f2bf(v.x), o1 = f2bf(v.y), o2 = f2bf(v.z), o3 = f2bf(v.w);
        unsigned lo = (unsigned)o0 | ((unsigned)o1 << 16);
        unsigned hi = (unsigned)o2 | ((unsigned)o3 << 16);
        ((uint2*)mvb)[i] = make_uint2(lo, hi);
    } else {
        int i = (bx - 48 - 8192) * 256 + tid;   // 1M float4s of out
        ((float4*)outz)[i] = make_float4(0.f, 0.f, 0.f, 0.f);
    }
}

// ---------------- GEMM1: S = Qhat(4096x128) * Khat(8192x128)^T ----------------
// Two-pass BK=64: stage Q/K half-tiles (32 KB) -> barrier -> 32 MFMA/wave ->
// barrier -> stage half 2 -> barrier -> 32 MFMA (acc carried). LDS = 34 KB
// (stage region unioned with Ps transpose buffer) -> 4 blocks/CU.
// XOR swizzle chunk ^= row&7 (128B rows) = gemm2's measured-0-conflict pattern.
// Epilogue: P = exp((S-bsq)*ms*0.125); denom via 16-lane butterfly + ONE
// atomicAdd/thread; tiled Pt store [pb][nb][128][128], 32KB contiguous.
__launch_bounds__(256, 4)
__global__ void gemm1_kernel(const u16* __restrict__ Qhat, const u16* __restrict__ Khat,
                             const float* __restrict__ bsq, const float* __restrict__ ms,
                             u16* __restrict__ Pt, float* __restrict__ denom) {
    __shared__ __align__(16) u16 smem[17408];   // 34 KB
    u16* Qs = smem;                 // [128][64] per pass
    u16* Ks = smem + 8192;          // [128][64] per pass

    const int tid  = threadIdx.x;
    const int l    = tid & 63;
    const int w    = tid >> 6;
    const int quad = l >> 4;
    const int l15  = l & 15;
    const int wm = w >> 1, wn = w & 1;
    const int p0 = blockIdx.x * 128;
    const int n0 = blockIdx.y * 128;

    const int rsub = tid >> 3;                      // 0..31 (row within round)
    const int csw  = (tid & 7) ^ (rsub & 7);        // swizzled source chunk

    f32x4 acc[4][4] = {};

    #pragma unroll
    for (int h = 0; h < 2; ++h) {
        if (h) __syncthreads();     // protect stage region from pass-0 readers
        #pragma unroll
        for (int rnd = 0; rnd < 4; ++rnd) {
            gld_lds16(Qhat + (size_t)(p0 + rnd * 32 + rsub) * 128 + h * 64 + csw * 8,
                      Qs + rnd * 2048 + w * 512);
            gld_lds16(Khat + (size_t)(n0 + rnd * 32 + rsub) * 128 + h * 64 + csw * 8,
                      Ks + rnd * 2048 + w * 512);
        }
        __syncthreads();
        #pragma unroll
        for (int kk = 0; kk < 2; ++kk) {
            bf16x8 a[4], b[4];
            #pragma unroll
            for (int mi = 0; mi < 4; ++mi) {
                int row = wm * 64 + mi * 16 + l15;
                a[mi] = *(const bf16x8*)(Qs + row * 64 + (((kk * 4 + quad) ^ (l15 & 7)) << 3));
            }
            #pragma unroll
            for (int ni = 0; ni < 4; ++ni) {
                int row = wn * 64 + ni * 16 + l15;
                b[ni] = *(const bf16x8*)(Ks + row * 64 + (((kk * 4 + quad) ^ (l15 & 7)) << 3));
            }
            #pragma unroll
            for (int mi = 0; mi < 4; ++mi)
                #pragma unroll
                for (int ni = 0; ni < 4; ++ni)
                    acc[mi][ni] = __builtin_amdgcn_mfma_f32_16x16x32_bf16(a[mi], b[ni], acc[mi][ni], 0, 0, 0);
        }
    }

    // per-lane epilogue constants
    float msv[4];
    #pragma unroll
    for (int ni = 0; ni < 4; ++ni)
        msv[ni] = ms[n0 + wn * 64 + ni * 16 + l15] * 0.125f;
    float bsv[4][4];
    #pragma unroll
    for (int mi = 0; mi < 4; ++mi)
        #pragma unroll
        for (int r = 0; r < 4; ++r)
            bsv[mi][r] = bsq[p0 + wm * 64 + mi * 16 + quad * 4 + r];

    __syncthreads();             // all waves done with stage region
    u16* Ps = smem;              // [128][136] padded, 34 KB
    float rowsum[4][4] = {};     // [mi][r] partial over this lane's 4 cols
    #pragma unroll
    for (int mi = 0; mi < 4; ++mi) {
        #pragma unroll
        for (int ni = 0; ni < 4; ++ni) {
            f32x4 v = acc[mi][ni];
            int col = wn * 64 + ni * 16 + l15;
            #pragma unroll
            for (int r = 0; r < 4; ++r) {
                int rowl = wm * 64 + mi * 16 + quad * 4 + r;
                float pv = __expf((v[r] - bsv[mi][r]) * msv[ni]);
                rowsum[mi][r] += pv;
                Ps[rowl * 136 + col] = f2bf(pv);
            }
        }
    }
    // butterfly full-reduce over the 16-lane l15 group
    #pragma unroll
    for (int mi = 0; mi < 4; ++mi)
        #pragma unroll
        for (int r = 0; r < 4; ++r) {
            float s = rowsum[mi][r];
            s += __shfl_xor(s, 1);
            s += __shfl_xor(s, 2);
            s += __shfl_xor(s, 4);
            s += __shfl_xor(s, 8);
            rowsum[mi][r] = s;
        }
    // one atomic per thread: lane l15 owns (mi,r) = (l15>>2, l15&3)
    {
        float myv = 0.f;
        #pragma unroll
        for (int mi = 0; mi < 4; ++mi)
            #pragma unroll
            for (int r = 0; r < 4; ++r)
                if (l15 == mi * 4 + r) myv = rowsum[mi][r];
        atomicAdd(&denom[p0 + wm * 64 + (l15 >> 2) * 16 + quad * 4 + (l15 & 3)], myv);
    }
    __syncthreads();

    // tiled Pt store: 32 KB contiguous per block
    {
        const size_t tileOff = ((size_t)blockIdx.x * 64 + blockIdx.y) * 16384;
        int row = tid >> 1, half = tid & 1;
        const u32x4* src = (const u32x4*)(Ps + row * 136 + half * 64);
        u32x4* dst = (u32x4*)(Pt + tileOff + row * 128 + half * 64);
        #pragma unroll
        for (int i = 0; i < 8; ++i) dst[i] = src[i];
    }
}

// ---------------- GEMM2: out += (mv_bf16(1024x8192) * Pt_tiled^T) / denom ----
// Split-K=4: 1024 blocks = 4 blocks/CU. XCD swizzle: linear id bits
// [2:0]=p_lo [5:3]=v [7:6]=p_hi [9:8]=kz so the 8 v-blocks sharing a Pt slab
// are 8 ids apart -> same XCD L2 (FETCH 271->103 MB measured). Divide-by-denom
// folded into the atomic epilogue (denom final before this kernel launches).
__launch_bounds__(256, 4)
__global__ void gemm2_kernel(const u16* __restrict__ Ab, const u16* __restrict__ Bt,
                             const float* __restrict__ denom, float* __restrict__ outacc) {
    __shared__ __align__(16) u16 As[128 * 64];
    __shared__ __align__(16) u16 Bs[128 * 64];

    const int tid  = threadIdx.x;
    const int l    = tid & 63;
    const int w    = tid >> 6;
    const int quad = l >> 4;
    const int l15  = l & 15;
    const int wm = w >> 1, wn = w & 1;

    const int lin = blockIdx.x + (blockIdx.y << 3) + (blockIdx.z << 8);
    const int vb  = (lin >> 3) & 7;
    const int pb  = (lin & 7) | (((lin >> 6) & 3) << 3);
    const int kz  = lin >> 8;
    const int v0 = vb * 128;
    const int p0 = pb * 128;
    const int kbeg = kz * (NMEM / 4);
    const int kend = kbeg + (NMEM / 4);

    const int rsub = tid >> 3;                      // 0..31
    const int csw  = (tid & 7) ^ (rsub & 7);        // swizzled source chunk

    f32x4 acc[4][4] = {};

    for (int k0 = kbeg; k0 < kend; k0 += 64) {
        const int nb = k0 >> 7;
        const int nh = (k0 >> 6) & 1;
        const u16* bsrc = Bt + ((size_t)pb * 64 + nb) * 16384 + nh * 64;
        __syncthreads();
        #pragma unroll
        for (int rnd = 0; rnd < 4; ++rnd) {
            gld_lds16(Ab + (size_t)(v0 + rnd * 32 + rsub) * NMEM + k0 + csw * 8,
                      As + rnd * 2048 + w * 512);
            gld_lds16(bsrc + (rnd * 32 + rsub) * 128 + csw * 8,
                      Bs + rnd * 2048 + w * 512);
        }
        __syncthreads();
        #pragma unroll
        for (int kk = 0; kk < 2; ++kk) {
            bf16x8 a[4], b[4];
            #pragma unroll
            for (int mi = 0; mi < 4; ++mi) {
                int row = wm * 64 + mi * 16 + l15;
                a[mi] = *(const bf16x8*)(As + row * 64 + (((kk * 4 + quad) ^ (l15 & 7)) << 3));
            }
            #pragma unroll
            for (int ni = 0; ni < 4; ++ni) {
                int row = wn * 64 + ni * 16 + l15;
                b[ni] = *(const bf16x8*)(Bs + row * 64 + (((kk * 4 + quad) ^ (l15 & 7)) << 3));
            }
            #pragma unroll
            for (int mi = 0; mi < 4; ++mi)
                #pragma unroll
                for (int ni = 0; ni < 4; ++ni)
                    acc[mi][ni] = __builtin_amdgcn_mfma_f32_16x16x32_bf16(a[mi], b[ni], acc[mi][ni], 0, 0, 0);
        }
    }

    float dinv[4];
    #pragma unroll
    for (int ni = 0; ni < 4; ++ni)
        dinv[ni] = 1.0f / denom[p0 + wn * 64 + ni * 16 + l15];

    #pragma unroll
    for (int mi = 0; mi < 4; ++mi) {
        #pragma unroll
        for (int ni = 0; ni < 4; ++ni) {
            int col = p0 + wn * 64 + ni * 16 + l15;
            f32x4 v = acc[mi][ni];
            #pragma unroll
            for (int r = 0; r < 4; ++r) {
                int row = v0 + wm * 64 + mi * 16 + quad * 4 + r;
                atomicAdd(&outacc[(size_t)row * HWPX + col], v[r] * dinv[ni]);
            }
        }
    }
}

// ---------------- launch ----------------
extern "C" void kernel_launch(void* const* d_in, const int* in_sizes, int n_in,
                              void* d_out, int out_size, void* d_ws, size_t ws_size,
                              hipStream_t stream) {
    const float* qk = (const float*)d_in[0];  // (1,64,64,64)
    const float* qe = (const float*)d_in[1];  // (1,64,64,64)
    const float* mk = (const float*)d_in[2];  // (1,64,2,64,64)
    const float* ms = (const float*)d_in[3];  // (1,1,2,64,64)
    const float* mv = (const float*)d_in[4];  // (1,2,512,2,64,64)
    float* out = (float*)d_out;               // (1,2,512,64,64)

    char* ws = (char*)d_ws;
    u16*   Pt    = (u16*)ws;                               // 64 MB  tiled [32][64][128][128] bf16
    u16*   mvb   = (u16*)(ws + ((size_t)64 << 20));        // 16 MB  [1024][8192] bf16
    u16*   Khat  = (u16*)(ws + ((size_t)80 << 20));        // 2 MB   [8192][128]  bf16
    u16*   Qhat  = (u16*)(ws + ((size_t)82 << 20));        // 1 MB   [4096][128]  bf16
    float* bsq   = (float*)(ws + ((size_t)83 << 20));      // 16 KB
    float* denom = (float*)(ws + ((size_t)83 << 20) + 65536); // 16 KB

    prep_all<<<48 + 8192 + 4096, 256, 0, stream>>>(qk, qe, mk, mv, Qhat, bsq, Khat, mvb,
                                                   denom, out);

    dim3 g1(HWPX / 128, NMEM / 128);   // (32, 64)
    gemm1_kernel<<<g1, 256, 0, stream>>>(Qhat, Khat, bsq, ms, Pt, denom);

    dim3 g2(8, 32, 4);  // 1024 blocks, swizzled decode inside
    gemm2_kernel<<<g2, 256, 0, stream>>>(mvb, Pt, denom, out);
}

// Round 7
// 231.843 us; speedup vs baseline: 1.1338x; 1.0048x over previous
//
#include <hip/hip_runtime.h>
#include <stdint.h>

// ---- types ----
typedef unsigned short u16;
typedef __attribute__((ext_vector_type(4))) float f32x4;
typedef __attribute__((ext_vector_type(8))) __bf16 bf16x8;
typedef __attribute__((ext_vector_type(4))) unsigned int u32x4;

#define HWPX 4096   // H*W pixels
#define NMEM 8192   // T*H*W memory slots
#define CKD  64
#define VROWS 1024  // NOBJ*CV

__device__ __forceinline__ u16 f2bf(float x) {
    union { float f; unsigned u; } v; v.f = x;
    unsigned r = v.u + 0x7FFFu + ((v.u >> 16) & 1u);
    return (u16)(r >> 16);
}

// async global->LDS, 16B per lane; lds base wave-uniform (HW adds lane*16)
__device__ __forceinline__ void gld_lds16(const void* g, void* l) {
    __builtin_amdgcn_global_load_lds(
        (const __attribute__((address_space(1))) uint32_t*)g,
        (__attribute__((address_space(3))) uint32_t*)l, 16, 0, 0);
}

// -------- fused prep: q (16) | k (32) | mv (8192) | zero-out (4096) --------
__global__ void prep_all(const float* __restrict__ qk, const float* __restrict__ qe,
                         const float* __restrict__ mk, const float* __restrict__ mv,
                         u16* __restrict__ Qhat, float* __restrict__ bsq,
                         u16* __restrict__ Khat, u16* __restrict__ mvb,
                         float* __restrict__ outz) {
    const int bx = blockIdx.x;
    const int tid = threadIdx.x;
    if (bx < 16) {
        int p = bx * 256 + tid;   // 4096
        float acc = 0.f;
        #pragma unroll 4
        for (int c = 0; c < CKD; ++c) {
            float k = qk[c * HWPX + p];
            float e = qe[c * HWPX + p];
            Qhat[p * 128 + c]      = f2bf(k * e);
            Qhat[p * 128 + 64 + c] = f2bf(e);
            acc += e * k * k;
        }
        bsq[p] = acc;
    } else if (bx < 48) {
        int n = (bx - 16) * 256 + tid;   // 8192
        #pragma unroll 4
        for (int c = 0; c < CKD; ++c) {
            float m = mk[c * NMEM + n];
            Khat[n * 128 + c]      = f2bf(2.f * m);
            Khat[n * 128 + 64 + c] = f2bf(-m * m);
        }
    } else if (bx < 48 + 8192) {
        int i = (bx - 48) * 256 + tid;   // 2M iterations, 4 floats each
        float4 v = ((const float4*)mv)[i];
        u16 o0 = f2bf(v.x), o1 = f2bf(v.y), o2 = f2bf(v.z), o3 = f2bf(v.w);
        unsigned lo = (unsigned)o0 | ((unsigned)o1 << 16);
        unsigned hi = (unsigned)o2 | ((unsigned)o3 << 16);
        ((uint2*)mvb)[i] = make_uint2(lo, hi);
    } else {
        int i = (bx - 48 - 8192) * 256 + tid;   // 1M float4s of out
        ((float4*)outz)[i] = make_float4(0.f, 0.f, 0.f, 0.f);
    }
}

// ---------------- GEMM1: S = Qhat(4096x128) * Khat(8192x128)^T ----------------
// Two-pass BK=64 staged via gld_lds, XOR swizzle (chunk ^= row&7), 34 KB LDS ->
// 4 blocks/CU. Epilogue: P = exp((S-bsq)*ms*0.125); per-wave row sums via
// 16-lane butterfly, written to EXCLUSIVE dpart[by*2+wn][p] slots (NO atomics).
// Pt stored TILED [pb][nb][128][128]; store is fully coalesced (1KB/wave/inst).
__launch_bounds__(256, 4)
__global__ void gemm1_kernel(const u16* __restrict__ Qhat, const u16* __restrict__ Khat,
                             const float* __restrict__ bsq, const float* __restrict__ ms,
                             u16* __restrict__ Pt, float* __restrict__ dpart) {
    __shared__ __align__(16) u16 smem[17408];   // 34 KB
    u16* Qs = smem;                 // [128][64] per pass
    u16* Ks = smem + 8192;          // [128][64] per pass

    const int tid  = threadIdx.x;
    const int l    = tid & 63;
    const int w    = tid >> 6;
    const int quad = l >> 4;
    const int l15  = l & 15;
    const int wm = w >> 1, wn = w & 1;
    const int p0 = blockIdx.x * 128;
    const int n0 = blockIdx.y * 128;

    const int rsub = tid >> 3;                      // 0..31 (row within round)
    const int csw  = (tid & 7) ^ (rsub & 7);        // swizzled source chunk

    f32x4 acc[4][4] = {};

    #pragma unroll
    for (int h = 0; h < 2; ++h) {
        if (h) __syncthreads();     // protect stage region from pass-0 readers
        #pragma unroll
        for (int rnd = 0; rnd < 4; ++rnd) {
            gld_lds16(Qhat + (size_t)(p0 + rnd * 32 + rsub) * 128 + h * 64 + csw * 8,
                      Qs + rnd * 2048 + w * 512);
            gld_lds16(Khat + (size_t)(n0 + rnd * 32 + rsub) * 128 + h * 64 + csw * 8,
                      Ks + rnd * 2048 + w * 512);
        }
        __syncthreads();
        #pragma unroll
        for (int kk = 0; kk < 2; ++kk) {
            bf16x8 a[4], b[4];
            #pragma unroll
            for (int mi = 0; mi < 4; ++mi) {
                int row = wm * 64 + mi * 16 + l15;
                a[mi] = *(const bf16x8*)(Qs + row * 64 + (((kk * 4 + quad) ^ (l15 & 7)) << 3));
            }
            #pragma unroll
            for (int ni = 0; ni < 4; ++ni) {
                int row = wn * 64 + ni * 16 + l15;
                b[ni] = *(const bf16x8*)(Ks + row * 64 + (((kk * 4 + quad) ^ (l15 & 7)) << 3));
            }
            #pragma unroll
            for (int mi = 0; mi < 4; ++mi)
                #pragma unroll
                for (int ni = 0; ni < 4; ++ni)
                    acc[mi][ni] = __builtin_amdgcn_mfma_f32_16x16x32_bf16(a[mi], b[ni], acc[mi][ni], 0, 0, 0);
        }
    }

    // per-lane epilogue constants
    float msv[4];
    #pragma unroll
    for (int ni = 0; ni < 4; ++ni)
        msv[ni] = ms[n0 + wn * 64 + ni * 16 + l15] * 0.125f;
    float bsv[4][4];
    #pragma unroll
    for (int mi = 0; mi < 4; ++mi)
        #pragma unroll
        for (int r = 0; r < 4; ++r)
            bsv[mi][r] = bsq[p0 + wm * 64 + mi * 16 + quad * 4 + r];

    __syncthreads();             // all waves done with stage region
    u16* Ps = smem;              // [128][136] padded, 34 KB
    float rowsum[4][4] = {};     // [mi][r] partial over this lane's 4 cols
    #pragma unroll
    for (int mi = 0; mi < 4; ++mi) {
        #pragma unroll
        for (int ni = 0; ni < 4; ++ni) {
            f32x4 v = acc[mi][ni];
            int col = wn * 64 + ni * 16 + l15;
            #pragma unroll
            for (int r = 0; r < 4; ++r) {
                int rowl = wm * 64 + mi * 16 + quad * 4 + r;
                float pv = __expf((v[r] - bsv[mi][r]) * msv[ni]);
                rowsum[mi][r] += pv;
                Ps[rowl * 136 + col] = f2bf(pv);
            }
        }
    }
    // butterfly full-reduce over the 16-lane l15 group
    #pragma unroll
    for (int mi = 0; mi < 4; ++mi)
        #pragma unroll
        for (int r = 0; r < 4; ++r) {
            float s = rowsum[mi][r];
            s += __shfl_xor(s, 1);
            s += __shfl_xor(s, 2);
            s += __shfl_xor(s, 4);
            s += __shfl_xor(s, 8);
            rowsum[mi][r] = s;
        }
    // exclusive-slot store: lane l15 owns (mi,r) = (l15>>2, l15&3); no atomics
    {
        float myv = 0.f;
        #pragma unroll
        for (int mi = 0; mi < 4; ++mi)
            #pragma unroll
            for (int r = 0; r < 4; ++r)
                if (l15 == mi * 4 + r) myv = rowsum[mi][r];
        int slice = blockIdx.y * 2 + wn;   // 0..127
        dpart[(size_t)slice * HWPX + p0 + wm * 64 + (l15 >> 2) * 16 + quad * 4 + (l15 & 3)] = myv;
    }
    __syncthreads();

    // tiled Pt store, fully coalesced: store i covers bytes [i*4K,(i+1)*4K) of
    // the 32KB tile; per wave each instruction writes 1KB contiguous.
    {
        const size_t tileOff = ((size_t)blockIdx.x * 64 + blockIdx.y) * 16384;  // u16 units
        #pragma unroll
        for (int i = 0; i < 8; ++i) {
            int row = i * 16 + (tid >> 4);
            const u32x4* src = (const u32x4*)(Ps + row * 136 + (tid & 15) * 8);
            u32x4* dst = (u32x4*)(Pt + tileOff + i * 2048 + tid * 8);
            *dst = *src;
        }
    }
}

// ---------------- GEMM2: out += (mv_bf16(1024x8192) * Pt_tiled^T) / denom ----
// Split-K=4: 1024 blocks = 4 blocks/CU. XCD swizzle: linear id bits
// [2:0]=p_lo [5:3]=v [7:6]=p_hi [9:8]=kz -> the 8 v-blocks sharing a Pt slab
// are 8 ids apart -> same XCD L2. denom reconstructed from dpart (128 slices)
// in a post-K-loop prologue; divide folded into the atomic epilogue.
__launch_bounds__(256, 4)
__global__ void gemm2_kernel(const u16* __restrict__ Ab, const u16* __restrict__ Bt,
                             const float* __restrict__ dpart, float* __restrict__ outacc) {
    __shared__ __align__(16) u16 As[128 * 64];
    __shared__ __align__(16) u16 Bs[128 * 64];

    const int tid  = threadIdx.x;
    const int l    = tid & 63;
    const int w    = tid >> 6;
    const int quad = l >> 4;
    const int l15  = l & 15;
    const int wm = w >> 1, wn = w & 1;

    const int lin = blockIdx.x + (blockIdx.y << 3) + (blockIdx.z << 8);
    const int vb  = (lin >> 3) & 7;
    const int pb  = (lin & 7) | (((lin >> 6) & 3) << 3);
    const int kz  = lin >> 8;
    const int v0 = vb * 128;
    const int p0 = pb * 128;
    const int kbeg = kz * (NMEM / 4);
    const int kend = kbeg + (NMEM / 4);

    const int rsub = tid >> 3;                      // 0..31
    const int csw  = (tid & 7) ^ (rsub & 7);        // swizzled source chunk

    f32x4 acc[4][4] = {};

    for (int k0 = kbeg; k0 < kend; k0 += 64) {
        const int nb = k0 >> 7;
        const int nh = (k0 >> 6) & 1;
        const u16* bsrc = Bt + ((size_t)pb * 64 + nb) * 16384 + nh * 64;
        __syncthreads();
        #pragma unroll
        for (int rnd = 0; rnd < 4; ++rnd) {
            gld_lds16(Ab + (size_t)(v0 + rnd * 32 + rsub) * NMEM + k0 + csw * 8,
                      As + rnd * 2048 + w * 512);
            gld_lds16(bsrc + (rnd * 32 + rsub) * 128 + csw * 8,
                      Bs + rnd * 2048 + w * 512);
        }
        __syncthreads();
        #pragma unroll
        for (int kk = 0; kk < 2; ++kk) {
            bf16x8 a[4], b[4];
            #pragma unroll
            for (int mi = 0; mi < 4; ++mi) {
                int row = wm * 64 + mi * 16 + l15;
                a[mi] = *(const bf16x8*)(As + row * 64 + (((kk * 4 + quad) ^ (l15 & 7)) << 3));
            }
            #pragma unroll
            for (int ni = 0; ni < 4; ++ni) {
                int row = wn * 64 + ni * 16 + l15;
                b[ni] = *(const bf16x8*)(Bs + row * 64 + (((kk * 4 + quad) ^ (l15 & 7)) << 3));
            }
            #pragma unroll
            for (int mi = 0; mi < 4; ++mi)
                #pragma unroll
                for (int ni = 0; ni < 4; ++ni)
                    acc[mi][ni] = __builtin_amdgcn_mfma_f32_16x16x32_bf16(a[mi], b[ni], acc[mi][ni], 0, 0, 0);
        }
    }

    // reconstruct 1/denom for this p-tile from the 128 dpart slices
    __syncthreads();                       // done reading As/Bs
    float* dtmp = (float*)As;              // 256 partials
    float* dinvs = (float*)Bs;             // 128 inverses
    {
        int p = tid & 127, h = tid >> 7;   // h: slice half
        float s = 0.f;
        #pragma unroll 8
        for (int sl = 0; sl < 64; ++sl)
            s += dpart[(size_t)(h * 64 + sl) * HWPX + p0 + p];
        dtmp[tid] = s;
    }
    __syncthreads();
    if (tid < 128) dinvs[tid] = 1.0f / (dtmp[tid] + dtmp[tid + 128]);
    __syncthreads();

    float dinv[4];
    #pragma unroll
    for (int ni = 0; ni < 4; ++ni)
        dinv[ni] = dinvs[wn * 64 + ni * 16 + l15];

    #pragma unroll
    for (int mi = 0; mi < 4; ++mi) {
        #pragma unroll
        for (int ni = 0; ni < 4; ++ni) {
            int col = p0 + wn * 64 + ni * 16 + l15;
            f32x4 v = acc[mi][ni];
            #pragma unroll
            for (int r = 0; r < 4; ++r) {
                int row = v0 + wm * 64 + mi * 16 + quad * 4 + r;
                atomicAdd(&outacc[(size_t)row * HWPX + col], v[r] * dinv[ni]);
            }
        }
    }
}

// ---------------- launch ----------------
extern "C" void kernel_launch(void* const* d_in, const int* in_sizes, int n_in,
                              void* d_out, int out_size, void* d_ws, size_t ws_size,
                              hipStream_t stream) {
    const float* qk = (const float*)d_in[0];  // (1,64,64,64)
    const float* qe = (const float*)d_in[1];  // (1,64,64,64)
    const float* mk = (const float*)d_in[2];  // (1,64,2,64,64)
    const float* ms = (const float*)d_in[3];  // (1,1,2,64,64)
    const float* mv = (const float*)d_in[4];  // (1,2,512,2,64,64)
    float* out = (float*)d_out;               // (1,2,512,64,64)

    char* ws = (char*)d_ws;
    u16*   Pt    = (u16*)ws;                               // 64 MB  tiled [32][64][128][128] bf16
    u16*   mvb   = (u16*)(ws + ((size_t)64 << 20));        // 16 MB  [1024][8192] bf16
    u16*   Khat  = (u16*)(ws + ((size_t)80 << 20));        // 2 MB   [8192][128]  bf16
    u16*   Qhat  = (u16*)(ws + ((size_t)82 << 20));        // 1 MB   [4096][128]  bf16
    float* bsq   = (float*)(ws + ((size_t)83 << 20));      // 16 KB
    float* dpart = (float*)(ws + ((size_t)83 << 20) + 65536); // 2 MB [128][4096] f32

    prep_all<<<48 + 8192 + 4096, 256, 0, stream>>>(qk, qe, mk, mv, Qhat, bsq, Khat, mvb, out);

    dim3 g1(HWPX / 128, NMEM / 128);   // (32, 64)
    gemm1_kernel<<<g1, 256, 0, stream>>>(Qhat, Khat, bsq, ms, Pt, dpart);

    dim3 g2(8, 32, 4);  // 1024 blocks, swizzled decode inside
    gemm2_kernel<<<g2, 256, 0, stream>>>(mvb, Pt, dpart, out);
}